// Round 11
// baseline (251.446 us; speedup 1.0000x reference)
//
#include <hip/hip_runtime.h>
#include <hip/hip_bf16.h>

// Pipeline (bf16 internal, fp32 in/out):
//   prep:   x fp32 -> xb bf16 (in d_out) + w_qkv -> wqkvT bf16 (one kernel)
//   gemm1:  qkv = xb @ wqkvT^T  (global_load_lds; Q cols scaled 0.125*log2e)
//   transpose_v: qkv V-cols -> vT bf16 [1024][4096]
//   attn:   flash causal, 64-row q-tile/block, grid 16x64 heavy-first.
//           K/V ping-pong staged via ASYNC global_load_lds with XOR-swizzled
//           LDS layout (chunk c of row r holds global chunk c^(r&7)) -> no
//           reg round-trip, no padding needed, balanced b128 reads.
//           ONE barrier per k-iter. S^T-form QK; O^T = V^T P^T; l via ones-MFMA.
//   transpose#2 + gemm2 -> out fp32
// WS (32MiB): qkv [0,24M); wqkvT [24,30M); vT [24,32M) alias after gemm1;
//   yb strided into qkv's dead V cols; wprojT aliases wqkvT after attn.

typedef unsigned short ushort_t;
typedef __attribute__((ext_vector_type(8))) __bf16 bf16x8;
typedef __attribute__((ext_vector_type(8))) unsigned short ushort8;
typedef __attribute__((ext_vector_type(4))) unsigned short ushort4v;
typedef __attribute__((ext_vector_type(4))) float f32x4;

#define LDK 72  // padded LDS row stride for Ps only (36 dwords)

__device__ inline unsigned short f2bf(float f) {
  union { float f; unsigned int u; } v;
  v.f = f;
  unsigned int r = v.u + 0x7fffu + ((v.u >> 16) & 1u);
  return (unsigned short)(r >> 16);
}

__device__ __forceinline__ void gl_lds16(const void* g, void* l) {
  __builtin_amdgcn_global_load_lds((const __attribute__((address_space(1))) void*)g,
                                   (__attribute__((address_space(3))) void*)l, 16, 0, 0);
}

// merged: cvt x (blocks 0..4095) + transpose w_qkv (blocks 4096..7167)
__global__ __launch_bounds__(256) void prep(const float* __restrict__ x,
                                            const float* __restrict__ w_qkv,
                                            ushort_t* __restrict__ xb,
                                            ushort_t* __restrict__ wqkvT) {
  __shared__ ushort_t tile[32][33];
  const int b = blockIdx.x;
  if (b < 4096) {
    const size_t i = ((size_t)b * 256 + threadIdx.x) * 4;
    const float4 v = *(const float4*)(x + i);
    ushort4v o;
    o.x = f2bf(v.x); o.y = f2bf(v.y); o.z = f2bf(v.z); o.w = f2bf(v.w);
    *(ushort4v*)(xb + i) = o;
  } else {
    const int b2 = b - 4096;
    const int c0 = (b2 % 96) * 32, r0 = (b2 / 96) * 32;
    const int tx = threadIdx.x & 31, ty = threadIdx.x >> 5;  // 32x8
    #pragma unroll
    for (int j = 0; j < 32; j += 8)
      tile[ty + j][tx] = f2bf(w_qkv[(size_t)(r0 + ty + j) * 3072 + c0 + tx]);
    __syncthreads();
    #pragma unroll
    for (int j = 0; j < 32; j += 8)
      wqkvT[(size_t)(c0 + ty + j) * 1024 + r0 + tx] = tile[tx][ty + j];
  }
}

// in fp32 [R][C] -> out bf16 [C][R]
__global__ __launch_bounds__(256) void transpose_f32_bf16(const float* __restrict__ in,
                                                          ushort_t* __restrict__ out,
                                                          int R, int C) {
  __shared__ ushort_t tile[32][33];
  const int r0 = blockIdx.y * 32, c0 = blockIdx.x * 32;
  const int tx = threadIdx.x, ty = threadIdx.y;  // block (32,8)
  #pragma unroll
  for (int j = 0; j < 32; j += 8)
    tile[ty + j][tx] = f2bf(in[(size_t)(r0 + ty + j) * C + c0 + tx]);
  __syncthreads();
  #pragma unroll
  for (int j = 0; j < 32; j += 8)
    out[(size_t)(c0 + ty + j) * R + r0 + tx] = tile[tx][ty + j];
}

// bf16 [rows, stride in_ld] -> bf16 [cols, stride out_ld]
__global__ __launch_bounds__(256) void transpose_bf16_ld(const ushort_t* __restrict__ in,
                                                         ushort_t* __restrict__ out,
                                                         int in_ld, int out_ld) {
  __shared__ ushort_t tile[32][33];
  const int r0 = blockIdx.y * 32, c0 = blockIdx.x * 32;
  const int tx = threadIdx.x, ty = threadIdx.y;
  #pragma unroll
  for (int j = 0; j < 32; j += 8)
    tile[ty + j][tx] = in[(size_t)(r0 + ty + j) * in_ld + c0 + tx];
  __syncthreads();
  #pragma unroll
  for (int j = 0; j < 32; j += 8)
    out[(size_t)(c0 + ty + j) * out_ld + r0 + tx] = tile[tx][ty + j];
}

// C bf16 = A(bf16) @ Bt^T, both staged async. Q-scale on blockIdx.x<8 (cols<1024).
__global__ __launch_bounds__(256) void gemm_bt_bf16out(const ushort_t* __restrict__ A,
                                                       const ushort_t* __restrict__ Bt,
                                                       ushort_t* __restrict__ C,
                                                       int M, int N, int K) {
  __shared__ __attribute__((aligned(16))) ushort_t As[128 * 64];
  __shared__ __attribute__((aligned(16))) ushort_t Bs[128 * 64];
  const int tid = threadIdx.x;
  const int lane = tid & 63;
  const int wave = tid >> 6;
  const int wy = wave >> 1, wx = wave & 1;
  const int quad = lane >> 4, l16 = lane & 15;
  const size_t bm = (size_t)blockIdx.y * 128;
  const size_t bn = (size_t)blockIdx.x * 128;

  const f32x4 fzero = {0.f, 0.f, 0.f, 0.f};
  f32x4 acc[4][4];
  #pragma unroll
  for (int i = 0; i < 4; ++i)
    #pragma unroll
    for (int j = 0; j < 4; ++j) acc[i][j] = fzero;

  for (int k0 = 0; k0 < K; k0 += 64) {
    #pragma unroll
    for (int i = 0; i < 4; ++i) {
      int c = (wave * 4 + i) * 64 + lane;
      int row = c >> 3, col = (c & 7) * 8;
      gl_lds16(A + (bm + row) * K + k0 + col, As + c * 8);
      gl_lds16(Bt + (bn + row) * K + k0 + col, Bs + c * 8);
    }
    __syncthreads();
    #pragma unroll
    for (int ks = 0; ks < 2; ++ks) {
      bf16x8 af[4], bb[4];
      #pragma unroll
      for (int mt = 0; mt < 4; ++mt)
        af[mt] = *(const bf16x8*)(As + (wy * 64 + mt * 16 + l16) * 64 + ks * 32 + quad * 8);
      #pragma unroll
      for (int nt = 0; nt < 4; ++nt)
        bb[nt] = *(const bf16x8*)(Bs + (wx * 64 + nt * 16 + l16) * 64 + ks * 32 + quad * 8);
      #pragma unroll
      for (int mt = 0; mt < 4; ++mt)
        #pragma unroll
        for (int nt = 0; nt < 4; ++nt)
          acc[mt][nt] = __builtin_amdgcn_mfma_f32_16x16x32_bf16(af[mt], bb[nt], acc[mt][nt], 0, 0, 0);
    }
    __syncthreads();
  }
  const float sc = (blockIdx.x < 8) ? 0.18033688f : 1.0f;  // 0.125*log2(e) for Q cols
  #pragma unroll
  for (int mt = 0; mt < 4; ++mt)
    #pragma unroll
    for (int nt = 0; nt < 4; ++nt)
      #pragma unroll
      for (int r = 0; r < 4; ++r)
        C[(bm + wy * 64 + mt * 16 + quad * 4 + r) * N + bn + wx * 64 + nt * 16 + l16] =
            f2bf(acc[mt][nt][r] * sc);
}

// A bf16 [M][K] row stride lda, Bt bf16 [N][K], C fp32. Both async.
__global__ __launch_bounds__(256) void gemm_bt_f32out(const ushort_t* __restrict__ A,
                                                      const ushort_t* __restrict__ Bt,
                                                      float* __restrict__ C,
                                                      int M, int N, int K, int lda) {
  __shared__ __attribute__((aligned(16))) ushort_t As[128 * 64];
  __shared__ __attribute__((aligned(16))) ushort_t Bs[128 * 64];
  const int tid = threadIdx.x;
  const int lane = tid & 63;
  const int wave = tid >> 6;
  const int wy = wave >> 1, wx = wave & 1;
  const int quad = lane >> 4, l16 = lane & 15;
  const size_t bm = (size_t)blockIdx.y * 128;
  const size_t bn = (size_t)blockIdx.x * 128;

  const f32x4 fzero = {0.f, 0.f, 0.f, 0.f};
  f32x4 acc[4][4];
  #pragma unroll
  for (int i = 0; i < 4; ++i)
    #pragma unroll
    for (int j = 0; j < 4; ++j) acc[i][j] = fzero;

  for (int k0 = 0; k0 < K; k0 += 64) {
    #pragma unroll
    for (int i = 0; i < 4; ++i) {
      int c = (wave * 4 + i) * 64 + lane;
      int row = c >> 3, col = (c & 7) * 8;
      gl_lds16(A + (bm + row) * lda + k0 + col, As + c * 8);
      gl_lds16(Bt + (bn + row) * K + k0 + col, Bs + c * 8);
    }
    __syncthreads();
    #pragma unroll
    for (int ks = 0; ks < 2; ++ks) {
      bf16x8 af[4], bb[4];
      #pragma unroll
      for (int mt = 0; mt < 4; ++mt)
        af[mt] = *(const bf16x8*)(As + (wy * 64 + mt * 16 + l16) * 64 + ks * 32 + quad * 8);
      #pragma unroll
      for (int nt = 0; nt < 4; ++nt)
        bb[nt] = *(const bf16x8*)(Bs + (wx * 64 + nt * 16 + l16) * 64 + ks * 32 + quad * 8);
      #pragma unroll
      for (int mt = 0; mt < 4; ++mt)
        #pragma unroll
        for (int nt = 0; nt < 4; ++nt)
          acc[mt][nt] = __builtin_amdgcn_mfma_f32_16x16x32_bf16(af[mt], bb[nt], acc[mt][nt], 0, 0, 0);
    }
    __syncthreads();
  }
  #pragma unroll
  for (int mt = 0; mt < 4; ++mt)
    #pragma unroll
    for (int nt = 0; nt < 4; ++nt)
      #pragma unroll
      for (int r = 0; r < 4; ++r)
        C[(bm + wy * 64 + mt * 16 + quad * 4 + r) * N + bn + wx * 64 + nt * 16 + l16] =
            acc[mt][nt][r];
}

// Flash causal attention. One 64-row q-tile per block, grid (16, 64) heavy-first.
// K/V ping-pong via ASYNC global_load_lds, XOR-swizzled layout:
//   LDS slot (row, chunk c) holds global chunk c^(row&7)  (chunk = 8 bf16 = 16B).
// One __syncthreads per k-iter (drains prev async loads + flips buffers).
// S^T-form QK; O^T = V^T P^T; l via ones-A MFMA (all-equal rows).
__global__ __launch_bounds__(256) void attn_fwd(const ushort_t* __restrict__ qkv,
                                                const ushort_t* __restrict__ vT,
                                                ushort_t* __restrict__ y) {
  __shared__ __attribute__((aligned(16))) ushort_t Ks[2][64 * 64];
  __shared__ __attribute__((aligned(16))) ushort_t Vs[2][64 * 64];
  __shared__ __attribute__((aligned(16))) ushort_t Ps[64 * LDK];  // also Q staging
  const int head = blockIdx.x;
  const int qt = (int)(gridDim.y - 1 - blockIdx.y);  // heavy tiles first
  const int qb = qt * 64;
  const int ntiles = qt + 1;
  const int tid = threadIdx.x;
  const int lane = tid & 63, wave = tid >> 6;  // 4 waves
  const int quad = lane >> 4, l16 = lane & 15;
  const size_t S3 = 3072;
  const int hoff = head * 64;
  const int rr = lane >> 3, cc = lane & 7;  // staging coords within an 8-row slab

  const f32x4 fzero = {0.f, 0.f, 0.f, 0.f};

  // stage Q tile: wave w writes rows w*16..+15 of Ps (read back by same wave only)
  #pragma unroll
  for (int i = 0; i < 2; ++i) {
    int row = wave * 16 + i * 8 + rr;
    *(ushort8*)(Ps + row * LDK + cc * 8) =
        *(const ushort8*)(qkv + (size_t)(qb + row) * S3 + hoff + cc * 8);
  }
  bf16x8 bq[2];
  #pragma unroll
  for (int ks = 0; ks < 2; ++ks)
    bq[ks] = *(const bf16x8*)(Ps + (wave * 16 + l16) * LDK + ks * 32 + quad * 8);

  // async-stage k-tile 0 into buf0 (swizzled source, lane-contiguous LDS dest)
  #pragma unroll
  for (int i = 0; i < 2; ++i) {
    int row = wave * 16 + i * 8 + rr;
    int sc = ((cc ^ (row & 7)) * 8);
    gl_lds16(qkv + (size_t)row * S3 + 1024 + hoff + sc, Ks[0] + row * 64 + cc * 8);
    gl_lds16(vT + (size_t)(hoff + row) * 4096 + sc, Vs[0] + row * 64 + cc * 8);
  }

  ushort8 ones_u;
  #pragma unroll
  for (int j = 0; j < 8; ++j) ones_u[j] = 0x3F80;  // bf16 1.0
  const bf16x8 aones = *(const bf16x8*)&ones_u;

  f32x4 o_acc[4], l_acc = fzero;
  #pragma unroll
  for (int nt = 0; nt < 4; ++nt) o_acc[nt] = fzero;

  for (int t = 0; t < ntiles; ++t) {
    const int cur = t & 1;
    __syncthreads();  // drains async loads into buf[cur]; all readers of buf[1-cur] done

    // issue async loads for tile t+1 into the other buffer (fly during compute)
    if (t + 1 < ntiles) {
      const int kb2 = (t + 1) * 64;
      #pragma unroll
      for (int i = 0; i < 2; ++i) {
        int row = wave * 16 + i * 8 + rr;
        int sc = ((cc ^ (row & 7)) * 8);
        gl_lds16(qkv + (size_t)(kb2 + row) * S3 + 1024 + hoff + sc,
                 Ks[1 - cur] + row * 64 + cc * 8);
        gl_lds16(vT + (size_t)(hoff + row) * 4096 + kb2 + sc,
                 Vs[1 - cur] + row * 64 + cc * 8);
      }
    }

    // S^T = K (Q*c)^T ; D-layout: row = kk_local = quad*4+r, col = q_local = l16
    f32x4 s[4];
    #pragma unroll
    for (int nt = 0; nt < 4; ++nt) s[nt] = fzero;
    #pragma unroll
    for (int ks = 0; ks < 2; ++ks) {
      #pragma unroll
      for (int nt = 0; nt < 4; ++nt) {
        const int krow = nt * 16 + l16;
        const int kch = (ks * 4 + quad) ^ (krow & 7);
        bf16x8 ak = *(const bf16x8*)(Ks[cur] + krow * 64 + kch * 8);
        s[nt] = __builtin_amdgcn_mfma_f32_16x16x32_bf16(ak, bq[ks], s[nt], 0, 0, 0);
      }
    }

    // P = exp2(S'), mask only diagonal-crossing tiles; packed b64 Ps stores
    const int kb = t * 64;
    const bool masked = (kb + 63 > qb + wave * 16);  // wave-uniform
    #pragma unroll
    for (int nt = 0; nt < 4; ++nt) {
      ushort4v pv;
      #pragma unroll
      for (int r = 0; r < 4; ++r) {
        float x = s[nt][r];
        if (masked) {
          int kkg = kb + nt * 16 + quad * 4 + r;
          x = (kkg <= qb + wave * 16 + l16) ? x : -30000.f;
        }
        union { float f; unsigned int u; } p;
        p.f = exp2f(x);
        pv[r] = (ushort_t)(p.u >> 16);  // truncate (p >= 0)
      }
      *(ushort4v*)(Ps + (wave * 16 + l16) * LDK + nt * 16 + quad * 4) = pv;
    }

    // O^T += V^T P^T ; l via ones-A MFMA (Ps rows wave-private: no barrier)
    #pragma unroll
    for (int ks = 0; ks < 2; ++ks) {
      bf16x8 bp = *(const bf16x8*)(Ps + (wave * 16 + l16) * LDK + ks * 32 + quad * 8);
      l_acc = __builtin_amdgcn_mfma_f32_16x16x32_bf16(aones, bp, l_acc, 0, 0, 0);
      #pragma unroll
      for (int nt = 0; nt < 4; ++nt) {
        const int vrow = nt * 16 + l16;
        const int vch = (ks * 4 + quad) ^ (vrow & 7);
        bf16x8 av = *(const bf16x8*)(Vs[cur] + vrow * 64 + vch * 8);
        o_acc[nt] = __builtin_amdgcn_mfma_f32_16x16x32_bf16(av, bp, o_acc[nt], 0, 0, 0);
      }
    }
  }

  // l_acc rows are all equal = l[q=l16]; no reduction needed
  const float inv = 1.0f / l_acc[0];
  // o_acc[nt][r] = O[q = qb+wave*16+l16][d = nt*16+quad*4+r] -> packed stores
  #pragma unroll
  for (int nt = 0; nt < 4; ++nt) {
    ushort4v ov;
    #pragma unroll
    for (int r = 0; r < 4; ++r) ov[r] = f2bf(o_acc[nt][r] * inv);
    *(ushort4v*)(y + (size_t)(qb + wave * 16 + l16) * S3 + hoff + nt * 16 + quad * 4) = ov;
  }
}

extern "C" void kernel_launch(void* const* d_in, const int* in_sizes, int n_in,
                              void* d_out, int out_size, void* d_ws, size_t ws_size,
                              hipStream_t stream) {
  const float* x = (const float*)d_in[0];       // [4096][1024] fp32
  const float* w_qkv = (const float*)d_in[1];   // [1024][3072] fp32
  const float* w_proj = (const float*)d_in[2];  // [1024][1024] fp32
  float* out = (float*)d_out;                   // [4096][1024] fp32

  ushort_t* ws = (ushort_t*)d_ws;
  ushort_t* qkv = ws;                            // [4096][3072]  [0, 24 MiB)
  ushort_t* wqkvT = ws + (size_t)4096 * 3072;    // [3072][1024]  [24, 30 MiB)
  ushort_t* vT = wqkvT;                          // [1024][4096]  [24, 32 MiB) alias after gemm1
  ushort_t* yb = qkv + 2048;                     // strided view into dead V cols (ld 3072)
  ushort_t* wprojT = wqkvT;                      // alias after attn
  ushort_t* xb = (ushort_t*)d_out;               // x bf16 scratch in d_out (dead before gemm2)

  prep<<<7168, 256, 0, stream>>>(x, w_qkv, xb, wqkvT);
  gemm_bt_bf16out<<<dim3(24, 32), 256, 0, stream>>>(xb, wqkvT, qkv, 4096, 3072, 1024);
  transpose_bf16_ld<<<dim3(32, 128), dim3(32, 8), 0, stream>>>(qkv + 2048, vT, 3072, 4096);
  attn_fwd<<<dim3(16, 64), 256, 0, stream>>>(qkv, vT, yb);
  transpose_f32_bf16<<<dim3(32, 32), dim3(32, 8), 0, stream>>>(w_proj, wprojT, 1024, 1024);
  gemm_bt_f32out<<<dim3(8, 32), 256, 0, stream>>>(yb, wprojT, out, 4096, 1024, 1024, 3072);
}